// Round 1
// baseline (84.498 us; speedup 1.0000x reference)
//
#include <hip/hip_runtime.h>
#include <math.h>

#define DIMS 128
#define KNEG 256
#define INV_TEMP 20.0f   // 1 / 0.05
#define EPSN 1e-12f

// One block (256 threads = 8 half-waves of 32 lanes) per output row n.
// Each half-wave gathers one candidate item row (512 B) with a single
// coalesced float4-per-lane load, computes dot(q,e) and dot(e,e) together
// (on-the-fly normalization of the table row), reduces across 32 lanes.
__global__ __launch_bounds__(256) void ssl_row_kernel(
    const float* __restrict__ out_emb,   // [N, 128]
    const float* __restrict__ table,     // [M, 128] raw (unnormalized)
    const float* __restrict__ w,         // [N]
    const int*   __restrict__ tgt,       // [N]
    const int*   __restrict__ negs,      // [N, 256]
    float*       __restrict__ loss_out,  // [N] = loss_per * w
    int max_row)                         // = M-1 (clip bound)
{
    const int n = blockIdx.x;
    const int t = threadIdx.x;

    __shared__ __align__(16) float q_lds[DIMS];
    __shared__ float logits[KNEG + 1];
    __shared__ int   nid[KNEG];
    __shared__ float red[8];

    const float wn = w[n];
    if (wn == 0.0f) {            // reference multiplies loss_per by w; w==0 rows contribute 0
        if (t == 0) loss_out[n] = 0.0f;
        return;
    }

    // ---- normalize q row into LDS ----
    float x = 0.0f;
    if (t < DIMS) x = out_emb[(size_t)n * DIMS + t];
    float ss = x * x;
    #pragma unroll
    for (int m = 1; m < 64; m <<= 1) ss += __shfl_xor(ss, m, 64);
    if ((t & 63) == 0) red[t >> 6] = ss;
    if (t < KNEG) nid[t] = negs[(size_t)n * KNEG + t];
    __syncthreads();
    const float inv_qn = 1.0f / fmaxf(sqrtf(red[0] + red[1]), EPSN);
    if (t < DIMS) q_lds[t] = x * inv_qn;
    __syncthreads();

    // ---- gather + logits ----
    const int hw   = t >> 5;   // half-wave id 0..7
    const int lane = t & 31;   // lane in half-wave
    const float4 qv = *(const float4*)(q_lds + lane * 4);
    const int tgtn = tgt[n];

    #pragma unroll 1
    for (int k = 0; k < 32; k += 2) {
        const int j1 = hw + (k << 3);
        const int j2 = j1 + 8;
        int id1 = (j1 == 0) ? tgtn : nid[j1 - 1];
        int id2 = nid[j2 - 1];
        int i1 = id1 - 1; i1 = i1 < 0 ? 0 : (i1 > max_row ? max_row : i1);
        int i2 = id2 - 1; i2 = i2 < 0 ? 0 : (i2 > max_row ? max_row : i2);
        const float4 e1 = ((const float4*)(table + (size_t)i1 * DIMS))[lane];
        const float4 e2 = ((const float4*)(table + (size_t)i2 * DIMS))[lane];
        float dq1 = qv.x*e1.x + qv.y*e1.y + qv.z*e1.z + qv.w*e1.w;
        float de1 = e1.x*e1.x + e1.y*e1.y + e1.z*e1.z + e1.w*e1.w;
        float dq2 = qv.x*e2.x + qv.y*e2.y + qv.z*e2.z + qv.w*e2.w;
        float de2 = e2.x*e2.x + e2.y*e2.y + e2.z*e2.z + e2.w*e2.w;
        #pragma unroll
        for (int m = 1; m < 32; m <<= 1) {
            dq1 += __shfl_xor(dq1, m, 64);
            de1 += __shfl_xor(de1, m, 64);
            dq2 += __shfl_xor(dq2, m, 64);
            de2 += __shfl_xor(de2, m, 64);
        }
        if (lane == 0) {
            logits[j1] = dq1 / fmaxf(sqrtf(de1), EPSN) * INV_TEMP;
            logits[j2] = dq2 / fmaxf(sqrtf(de2), EPSN) * INV_TEMP;
        }
    }
    if (hw == 0) {   // j = 256 (last negative)
        int id = nid[KNEG - 1];
        int i1 = id - 1; i1 = i1 < 0 ? 0 : (i1 > max_row ? max_row : i1);
        const float4 e1 = ((const float4*)(table + (size_t)i1 * DIMS))[lane];
        float dq1 = qv.x*e1.x + qv.y*e1.y + qv.z*e1.z + qv.w*e1.w;
        float de1 = e1.x*e1.x + e1.y*e1.y + e1.z*e1.z + e1.w*e1.w;
        #pragma unroll
        for (int m = 1; m < 32; m <<= 1) {
            dq1 += __shfl_xor(dq1, m, 64);
            de1 += __shfl_xor(de1, m, 64);
        }
        if (lane == 0) logits[KNEG] = dq1 / fmaxf(sqrtf(de1), EPSN) * INV_TEMP;
    }
    __syncthreads();

    // ---- stable LSE over 257 logits ----
    float mx = logits[t];
    if (t == 0) mx = fmaxf(mx, logits[KNEG]);
    #pragma unroll
    for (int m = 1; m < 64; m <<= 1) mx = fmaxf(mx, __shfl_xor(mx, m, 64));
    if ((t & 63) == 0) red[t >> 6] = mx;
    __syncthreads();
    if (t == 0) red[4] = fmaxf(fmaxf(red[0], red[1]), fmaxf(red[2], red[3]));
    __syncthreads();
    mx = red[4];

    float p = expf(logits[t] - mx);
    if (t == 0) p += expf(logits[KNEG] - mx);
    #pragma unroll
    for (int m = 1; m < 64; m <<= 1) p += __shfl_xor(p, m, 64);
    if ((t & 63) == 0) red[t >> 6] = p;
    __syncthreads();
    if (t == 0) {
        const float s   = red[0] + red[1] + red[2] + red[3];
        const float lse = mx + logf(s);
        loss_out[n] = (lse - logits[0]) * wn;   // loss_per * w
    }
}

// Deterministic final reduction: sum(loss*w) / sum(w)
__global__ __launch_bounds__(256) void ssl_reduce_kernel(
    const float* __restrict__ loss,  // [N]
    const float* __restrict__ w,     // [N]
    float* __restrict__ out, int n)
{
    __shared__ float red[8];
    const int t = threadIdx.x;
    float sl = 0.0f, sw = 0.0f;
    for (int i = t; i < n; i += 256) { sl += loss[i]; sw += w[i]; }
    #pragma unroll
    for (int m = 1; m < 64; m <<= 1) {
        sl += __shfl_xor(sl, m, 64);
        sw += __shfl_xor(sw, m, 64);
    }
    if ((t & 63) == 0) { red[t >> 6] = sl; red[4 + (t >> 6)] = sw; }
    __syncthreads();
    if (t == 0) {
        const float SL = red[0] + red[1] + red[2] + red[3];
        const float SW = red[4] + red[5] + red[6] + red[7];
        out[0] = SL / SW;
    }
}

extern "C" void kernel_launch(void* const* d_in, const int* in_sizes, int n_in,
                              void* d_out, int out_size, void* d_ws, size_t ws_size,
                              hipStream_t stream) {
    const float* out_emb = (const float*)d_in[0];   // [16,256,128]
    const float* table   = (const float*)d_in[1];   // [1000001,128]
    const float* w       = (const float*)d_in[2];   // [16,256]
    const int*   tgt     = (const int*)d_in[3];     // [16,256]
    const int*   negs    = (const int*)d_in[4];     // [4096,256]

    const int N = in_sizes[2];                       // 4096
    const int rows = in_sizes[1] / DIMS;             // 1000001
    const int max_row = rows - 1;

    float* loss_ws = (float*)d_ws;                   // N floats

    ssl_row_kernel<<<N, 256, 0, stream>>>(out_emb, table, w, tgt, negs, loss_ws, max_row);
    ssl_reduce_kernel<<<1, 256, 0, stream>>>(loss_ws, w, (float*)d_out, N);
}